// Round 2
// baseline (9362.145 us; speedup 1.0000x reference)
//
#include <hip/hip_runtime.h>

#define NUM_Q 8
#define D     1024
#define CDIM  32
#define K     1024
#define B     16
#define T     4096
#define QC    (NUM_Q*CDIM)   // 256
#define NTOK  (B*T)          // 65536
#define THR_MARGIN 2e-3f

// ---------------- K0a: normalized codebook fp64 + fp32 ----------------
__global__ void k_cbn(const float* __restrict__ cb, double* __restrict__ cbn64,
                      float* __restrict__ cbn32) {
  int i = blockIdx.x*256 + threadIdx.x;   // q*K + k
  if (i >= NUM_Q*K) return;
  const float* v = cb + (size_t)i*CDIM;
  double s = 0.0;
  for (int c = 0; c < CDIM; ++c) { double x = (double)v[c]; s += x*x; }
  double n = fmax(sqrt(s), 1e-12);
  for (int c = 0; c < CDIM; ++c) {
    double e = (double)v[c] / n;
    cbn64[(size_t)i*CDIM + c] = e;
    cbn32[(size_t)i*CDIM + c] = (float)e;
  }
}

// ---------------- K0b: zero loss/cnt, obsum fp32 ----------------
__global__ void k_prep(const float* __restrict__ out_b, float* __restrict__ obs,
                       double* __restrict__ lac, int* __restrict__ cnt) {
  int i = blockIdx.x*256 + threadIdx.x;
  if (i < NUM_Q) { lac[i] = 0.0; cnt[i] = 0; }
  if (i < D) {
    double s = 0.0;
    for (int q = 0; q < NUM_Q; ++q) s += (double)out_b[q*D + i];
    obs[i] = (float)s;
  }
}

// ---------------- K1a: M[q][p] = in_w[q]@out_w[p] (fp64), vb = in_w[q]@out_b[p] ----------
__global__ void k_M(const float* __restrict__ in_w, const float* __restrict__ out_w,
                    const float* __restrict__ out_b, double* __restrict__ M,
                    double* __restrict__ vb) {
  int i = blockIdx.x*256 + threadIdx.x;   // 8*8*32*32 = 65536
  int e = i & 31; int c = (i >> 5) & 31; int p = (i >> 10) & 7; int q = i >> 13;
  if (q >= NUM_Q) return;
  const float* wi = in_w + ((size_t)q*CDIM + c)*D;
  const float* wo = out_w + (size_t)p*D*CDIM + e;
  double s = 0.0;
  for (int d = 0; d < D; ++d) s += (double)wi[d] * (double)wo[(size_t)d*CDIM];
  M[i] = s;
  if (e == 0) {
    const float* ob = out_b + (size_t)p*D;
    double sb = 0.0;
    for (int d = 0; d < D; ++d) sb += (double)wi[d] * (double)ob[d];
    vb[(q*8 + p)*CDIM + c] = sb;
  }
}

// ---------------- K1b: folded correction tables Mc = M@cb^T + vb (fp64 + fp32) ----------
__global__ void k_Mcbf(const double* __restrict__ M, const float* __restrict__ cb,
                       const double* __restrict__ vb, double* __restrict__ Mc64,
                       float* __restrict__ Mc32) {
  long i = blockIdx.x*(long)256 + threadIdx.x;  // 8*8*1024*32 = 2097152
  if (i >= (long)NUM_Q*NUM_Q*K*CDIM) return;
  int c = (int)(i & 31); long r = i >> 5;
  int k = (int)(r & (K-1)); r >>= 10;
  int p = (int)(r & 7); int q = (int)(r >> 3);
  const double* m = M + (((size_t)(q*8 + p)*CDIM + c)*CDIM);
  const float* v = cb + ((size_t)p*K + k)*CDIM;
  double s = 0.0;
  for (int e = 0; e < CDIM; ++e) s += m[e] * (double)v[e];
  double f = s + vb[(q*8 + p)*CDIM + c];       // identical to runtime (mc+vb) fold
  size_t o = ((size_t)(q*8 + p)*K + k)*CDIM + c;
  Mc64[o] = f;
  Mc32[o] = (float)f;
}

// ---------------- K1c: OCB[q][k][d] = out_w[q]@cb[q][k]  (fp32) ----------
__global__ __launch_bounds__(256) void k_ocb(const float* __restrict__ out_w,
                                             const float* __restrict__ cb,
                                             float* __restrict__ OCB) {
  __shared__ float cr[CDIM];
  int qk = blockIdx.x;            // q*K + k
  int qq = qk >> 10;
  int tid = threadIdx.x;
  if (tid < CDIM) cr[tid] = cb[(size_t)qk*CDIM + tid];
  __syncthreads();
  for (int r = 0; r < 4; ++r) {
    int d = tid + r*256;
    const float4* w4 = (const float4*)(out_w + ((size_t)(qq*D + d))*CDIM);
    float s0 = 0.f, s1 = 0.f, s2 = 0.f, s3 = 0.f;
    #pragma unroll
    for (int e = 0; e < 8; ++e) {
      float4 w = w4[e];
      s0 += w.x*cr[4*e]; s1 += w.y*cr[4*e+1]; s2 += w.z*cr[4*e+2]; s3 += w.w*cr[4*e+3];
    }
    OCB[(size_t)qk*D + d] = (s0 + s1) + (s2 + s3);
  }
}

// ---------------- K2: P[b][j][t] = in_w_flat[j]@x[b][:,t]  fp32 ----------
#define JT  64
#define DCH 128
__global__ __launch_bounds__(256) void k_P(const float* __restrict__ x,
                                           const float* __restrict__ in_w,
                                           float* __restrict__ P) {
  __shared__ float lw[DCH][JT + 4];       // pad 68 -> b128-aligned rows, cheap write conflicts
  int j0 = blockIdx.x*JT;
  int t  = blockIdx.y*256 + threadIdx.x;
  int b  = blockIdx.z;
  float acc[JT];
  #pragma unroll
  for (int j = 0; j < JT; ++j) acc[j] = 0.f;
  for (int d0 = 0; d0 < D; d0 += DCH) {
    __syncthreads();
    for (int u = threadIdx.x; u < JT*DCH; u += 256) {
      int jj = u >> 7, dd = u & 127;      // coalesced global read, strided LDS write
      lw[dd][jj] = in_w[(size_t)(j0 + jj)*D + d0 + dd];
    }
    __syncthreads();
    const float* xp = x + ((size_t)(b*D + d0))*T + t;
    for (int dd = 0; dd < DCH; ++dd) {
      float xv = xp[(size_t)dd*T];
      const float4* w4 = (const float4*)(&lw[dd][0]);
      #pragma unroll
      for (int g = 0; g < 16; ++g) {
        float4 w = w4[g];
        acc[4*g+0] += xv*w.x; acc[4*g+1] += xv*w.y;
        acc[4*g+2] += xv*w.z; acc[4*g+3] += xv*w.w;
      }
    }
  }
  float* Pp = P + ((size_t)(b*QC + j0))*T + t;
  #pragma unroll
  for (int j = 0; j < JT; ++j) Pp[(size_t)j*T] = acc[j];
}

// ---------------- K3A: fp32 scan + top-2 margin + flag ----------
// 2 threads per token (h = lane>>5 scans half of each LDS chunk), merge via shfl_xor(32).
__global__ __launch_bounds__(256) void k_stageA(
    int q, const float* __restrict__ P, const float* __restrict__ Mc32,
    const float* __restrict__ in_b, const float* __restrict__ cbn32,
    const float* __restrict__ cb, int* __restrict__ idxw,
    double* __restrict__ lac, float* __restrict__ out_idx,
    int* __restrict__ cnt, int* __restrict__ flags) {
  __shared__ float cbl[256*CDIM];         // 32 KB chunk of normalized codebook
  int tid = threadIdx.x;
  int lane = tid & 63, wv = tid >> 6;
  int h = lane >> 5, il = lane & 31;
  int i = blockIdx.x*128 + wv*32 + il;    // token id (each token owned by 2 lanes)
  int b = i >> 12, t = i & (T-1);

  float z[CDIM];
  const float* Pp = P + ((size_t)(b*QC + q*CDIM))*T + t;
  #pragma unroll
  for (int c = 0; c < CDIM; ++c) z[c] = Pp[(size_t)c*T] + in_b[q*CDIM + c];

  for (int p = 0; p < q; ++p) {
    int kp = idxw[p*NTOK + i];
    const float4* mc = (const float4*)(Mc32 + ((size_t)((q*8 + p)*K + kp))*CDIM);
    #pragma unroll
    for (int g = 0; g < 8; ++g) {
      float4 m = mc[g];
      z[4*g+0] -= m.x; z[4*g+1] -= m.y; z[4*g+2] -= m.z; z[4*g+3] -= m.w;
    }
  }
  float ss = 0.f;
  #pragma unroll
  for (int c = 0; c < CDIM; ++c) ss += z[c]*z[c];
  float rn = 1.f / fmaxf(sqrtf(ss), 1e-12f);

  // scan unnormalized (rn > 0 constant per token: same argmax ordering)
  float best = -1e30f, second = -1e30f; int bi = 0;
  for (int cc = 0; cc < 4; ++cc) {
    __syncthreads();
    const float4* src4 = (const float4*)(cbn32 + (size_t)(q*K + cc*256)*CDIM);
    float4* dst4 = (float4*)cbl;
    for (int r = 0; r < 8; ++r) dst4[tid + r*256] = src4[tid + r*256];
    __syncthreads();
    int kb = cc*256 + h*128;
    const float* cp = cbl + (size_t)h*128*CDIM;
    for (int kk = 0; kk < 128; ++kk) {
      const float4* r4 = (const float4*)(cp + kk*CDIM);
      float s0 = 0.f, s1 = 0.f, s2 = 0.f, s3 = 0.f;
      #pragma unroll
      for (int e = 0; e < 8; ++e) {
        float4 a = r4[e];
        s0 += z[4*e]*a.x; s1 += z[4*e+1]*a.y; s2 += z[4*e+2]*a.z; s3 += z[4*e+3]*a.w;
      }
      float sim = (s0 + s1) + (s2 + s3);
      if (sim > best) { second = best; best = sim; bi = kb + kk; }
      else if (sim > second) second = sim;
    }
  }
  // merge the two halves (exact ties land under margin -> phase B resolves)
  float ob2 = __shfl_xor(best, 32, 64);
  float os2 = __shfl_xor(second, 32, 64);
  int   ok2 = __shfl_xor(bi, 32, 64);
  if (ob2 > best || (ob2 == best && ok2 < bi)) {
    second = fmaxf(best, os2); best = ob2; bi = ok2;
  } else {
    second = fmaxf(second, ob2);
  }
  float margin = (best - second)*rn;
  bool flag = !(margin >= THR_MARGIN) || !(ss >= 1e-3f);

  double l = 0.0;
  if (h == 0) {
    idxw[q*NTOK + i] = bi;
    out_idx[(size_t)q*NTOK + i] = (float)bi;
    const float* cv = cb + ((size_t)(q*K + bi))*CDIM;
    float lf = 0.f;
    #pragma unroll
    for (int c = 0; c < CDIM; ++c) { float d2 = z[c] - cv[c]; lf += d2*d2; }
    l = (double)lf;
    if (flag) {
      int pos = atomicAdd(&cnt[q], 1);
      flags[q*NTOK + pos] = i;
    }
  }
  #pragma unroll
  for (int off = 32; off > 0; off >>= 1) l += __shfl_down(l, off, 64);
  if (lane == 0) atomicAdd(&lac[q], l);
}

// ---------------- K3B: exact fp64 re-decision for flagged tokens ----------
__global__ __launch_bounds__(256) void k_stageB(
    int q, const float* __restrict__ x, const float* __restrict__ in_w,
    const float* __restrict__ in_b, const double* __restrict__ Mc64,
    const double* __restrict__ cbn64, int* __restrict__ idxw,
    float* __restrict__ out_idx, const int* __restrict__ cnt,
    const int* __restrict__ flags) {
  __shared__ double part[CDIM][8];
  __shared__ double esh[CDIM];
  __shared__ double rv[256];
  __shared__ int    rk[256];
  int tid = threadIdx.x;
  int cq = cnt[q];
  for (int j = blockIdx.x; j < cq; j += gridDim.x) {
    int i = flags[q*NTOK + j];
    int b = i >> 12, t = i & (T-1);
    int c = tid & 31, g = tid >> 5;
    const float* wr = in_w + ((size_t)(q*CDIM + c))*D + g*128;
    const float* xc = x + ((size_t)(b*D + g*128))*T + t;
    double sp = 0.0;
    for (int d = 0; d < 128; ++d) sp += (double)wr[d]*(double)xc[(size_t)d*T];
    part[c][g] = sp;
    __syncthreads();
    if (tid < CDIM) {
      double zz = 0.0;
      for (int gg = 0; gg < 8; ++gg) zz += part[tid][gg];
      zz += (double)in_b[q*CDIM + tid];
      for (int p = 0; p < q; ++p) {
        int kp = idxw[p*NTOK + i];
        zz -= Mc64[((size_t)((q*8 + p)*K + kp))*CDIM + tid];
      }
      part[tid][0] = zz;
    }
    __syncthreads();
    if (tid == 0) {
      double s = 0.0;
      for (int c2 = 0; c2 < CDIM; ++c2) s += part[c2][0]*part[c2][0];
      double nn = fmax(sqrt(s), 1e-12);
      for (int c2 = 0; c2 < CDIM; ++c2) esh[c2] = part[c2][0]/nn;
    }
    __syncthreads();
    double bv = -1e300; int bk = 0;
    #pragma unroll
    for (int r = 0; r < 4; ++r) {
      int k = tid*4 + r;
      const double* cr = cbn64 + ((size_t)(q*K + k))*CDIM;
      double s = 0.0;
      #pragma unroll
      for (int e = 0; e < CDIM; ++e) s += esh[e]*cr[e];
      if (s > bv || (s == bv && k < bk)) { bv = s; bk = k; }
    }
    rv[tid] = bv; rk[tid] = bk;
    __syncthreads();
    for (int st = 128; st > 0; st >>= 1) {
      if (tid < st) {
        double ov = rv[tid + st]; int ok = rk[tid + st];
        if (ov > rv[tid] || (ov == rv[tid] && ok < rk[tid])) { rv[tid] = ov; rk[tid] = ok; }
      }
      __syncthreads();
    }
    if (tid == 0) {
      idxw[q*NTOK + i] = rk[0];
      out_idx[(size_t)q*NTOK + i] = (float)rk[0];
    }
    __syncthreads();
  }
}

// ---------------- K4: out[b][d][t] = obsum[d] + sum_q OCB[q][idx_q][d] ----------
__global__ __launch_bounds__(256) void k_out2(const int* __restrict__ idxw,
                                              const float* __restrict__ OCB,
                                              const float* __restrict__ obs,
                                              float* __restrict__ out) {
  int b = blockIdx.y;
  int t0 = blockIdx.x*16;
  int d0 = threadIdx.x*4;
  float4 ob = *(const float4*)(obs + d0);
  float res[16][4];
  #pragma unroll
  for (int j = 0; j < 16; ++j) {
    int i = (b << 12) + t0 + j;
    float4 a = ob;
    #pragma unroll
    for (int p = 0; p < NUM_Q; ++p) {
      int kp = idxw[p*NTOK + i];
      float4 v = *(const float4*)(OCB + ((size_t)(p*K + kp))*D + d0);
      a.x += v.x; a.y += v.y; a.z += v.z; a.w += v.w;
    }
    res[j][0] = a.x; res[j][1] = a.y; res[j][2] = a.z; res[j][3] = a.w;
  }
  #pragma unroll
  for (int dd = 0; dd < 4; ++dd) {
    float* op = out + ((size_t)(b*D + d0 + dd))*T + t0;
    #pragma unroll
    for (int g = 0; g < 4; ++g) {
      float4 w = make_float4(res[4*g][dd], res[4*g+1][dd], res[4*g+2][dd], res[4*g+3][dd]);
      *(float4*)(op + 4*g) = w;
    }
  }
}

// ---------------- K5: losses ----------
__global__ void k_loss(const double* __restrict__ lac, float* __restrict__ out_l) {
  int i = threadIdx.x;
  if (i < NUM_Q)
    out_l[i] = (float)(1.25 * lac[i] / ((double)B * CDIM * T));
}

extern "C" void kernel_launch(void* const* d_in, const int* in_sizes, int n_in,
                              void* d_out, int out_size, void* d_ws, size_t ws_size,
                              hipStream_t stream) {
  const float* x     = (const float*)d_in[0];
  const float* in_w  = (const float*)d_in[1];
  const float* in_b  = (const float*)d_in[2];
  const float* out_w = (const float*)d_in[3];
  const float* out_b = (const float*)d_in[4];
  const float* cb    = (const float*)d_in[5];
  float* out = (float*)d_out;

  char* ws = (char*)d_ws;
  float*  P     = (float*) (ws + 0);           //  64 MB [B][QC][T]
  float*  OCB   = (float*) (ws + 67108864);    //  32 MB [q][K][D]
  double* Mc64  = (double*)(ws + 100663296);   //  16 MB [q][p][K][CDIM]
  float*  Mc32  = (float*) (ws + 117440512);   //   8 MB
  double* cbn64 = (double*)(ws + 125829120);   //   2 MB
  float*  cbn32 = (float*) (ws + 127926272);   //   1 MB
  double* M     = (double*)(ws + 128974848);   // 512 KB
  int*    idxw  = (int*)   (ws + 129499136);   //   2 MB [q][B*T]
  int*    flags = (int*)   (ws + 131596288);   //   2 MB [q][B*T]
  double* vb    = (double*)(ws + 133693440);   //  16 KB
  float*  obs   = (float*) (ws + 133709824);   //   4 KB
  double* lac   = (double*)(ws + 133718016);   //  64 B
  int*    cnt   = (int*)   (ws + 133718144);   //  32 B

  float* out_q = out;                // [B][D][T]
  float* out_i = out + 67108864;     // [NUM_Q][B][T]
  float* out_l = out + 67633152;     // [NUM_Q]

  k_cbn  <<<dim3(32),   dim3(256), 0, stream>>>(cb, cbn64, cbn32);
  k_prep <<<dim3(4),    dim3(256), 0, stream>>>(out_b, obs, lac, cnt);
  k_M    <<<dim3(256),  dim3(256), 0, stream>>>(in_w, out_w, out_b, M, vb);
  k_Mcbf <<<dim3(8192), dim3(256), 0, stream>>>(M, cb, vb, Mc64, Mc32);
  k_ocb  <<<dim3(8192), dim3(256), 0, stream>>>(out_w, cb, OCB);
  k_P    <<<dim3(QC/JT, T/256, B), dim3(256), 0, stream>>>(x, in_w, P);
  for (int q = 0; q < NUM_Q; ++q) {
    k_stageA<<<dim3(NTOK/128), dim3(256), 0, stream>>>(q, P, Mc32, in_b, cbn32, cb,
                                                       idxw, lac, out_i, cnt, flags);
    k_stageB<<<dim3(2048), dim3(256), 0, stream>>>(q, x, in_w, in_b, Mc64, cbn64,
                                                   idxw, out_i, cnt, flags);
  }
  k_out2 <<<dim3(T/16, B), dim3(256), 0, stream>>>(idxw, OCB, obs, out_q);
  k_loss <<<dim3(1), dim3(64), 0, stream>>>(lac, out_l);
}